// Round 1
// baseline (325.895 us; speedup 1.0000x reference)
//
#include <hip/hip_runtime.h>

// EdgeBlock: out[e] = (relu(relu(x@W0+b0)@W1+b1))@W2+b2, x = [edge|recv|send|glob] (64)
// Strategy: bf16 hi/lo split MFMA (fp32-equivalent accuracy), transposed products so
// inter-layer data stays lane-local (transpose folded into weight-frag packing bijection).

typedef float f32x4 __attribute__((ext_vector_type(4)));
typedef short short8 __attribute__((ext_vector_type(8)));

#define E_DIV16(x) ((x) >> 4)

__device__ __forceinline__ unsigned short f2bf(float f) {
    union { float f; unsigned int u; } v; v.f = f;
    unsigned int u = v.u;
    u += 0x7FFFu + ((u >> 16) & 1u);   // RNE
    return (unsigned short)(u >> 16);
}
__device__ __forceinline__ float bf2f(unsigned short b) {
    union { unsigned int u; float f; } v; v.u = ((unsigned int)b) << 16;
    return v.f;
}

// ---------------- prep: pack weights/biases into MFMA fragment layout in ws -------------
// ws layout (ushort units):
//   w0h[4096] w0l[4096] w1h[4096] w1l[4096] w2h[1024] w2l[1024]   (frags: [f][lane][j])
// then (float units, byte 36864):
//   b0f[64][16] b1f[64][16] b2f[64][4]
__global__ void prep_kernel(const float* __restrict__ W0, const float* __restrict__ b0,
                            const float* __restrict__ W1, const float* __restrict__ b1,
                            const float* __restrict__ W2, const float* __restrict__ b2,
                            void* __restrict__ ws) {
    unsigned short* w0h = (unsigned short*)ws;
    unsigned short* w0l = w0h + 4096;
    unsigned short* w1h = w0h + 8192;
    unsigned short* w1l = w0h + 12288;
    unsigned short* w2h = w0h + 16384;
    unsigned short* w2l = w0h + 17408;
    float* b0f = (float*)(w0h + 18432);
    float* b1f = b0f + 1024;
    float* b2f = b0f + 2048;
    const int tid = threadIdx.x;

    // W0 frags: A[m=hid][k=in] = W0[k][m]; k-slot map mu0 = 32*kt + 8*g + j
    for (int idx = tid; idx < 4096; idx += 256) {
        int j = idx & 7, lane = (idx >> 3) & 63, f = idx >> 9;
        int t = f >> 1, kt = f & 1, mr = lane & 15, g = lane >> 4;
        float w = W0[(32 * kt + 8 * g + j) * 64 + (16 * t + mr)];
        unsigned short h = f2bf(w);
        w0h[idx] = h;
        w0l[idx] = f2bf(w - bf2f(h));
    }
    // W1 frags: k-slot map mu = 16*(2*kt + (j>>2)) + 4*g + (j&3)  (matches layer-0 output layout)
    for (int idx = tid; idx < 4096; idx += 256) {
        int j = idx & 7, lane = (idx >> 3) & 63, f = idx >> 9;
        int t = f >> 1, kt = f & 1, mr = lane & 15, g = lane >> 4;
        int mu = 16 * (2 * kt + (j >> 2)) + 4 * g + (j & 3);
        float w = W1[mu * 64 + (16 * t + mr)];
        unsigned short h = f2bf(w);
        w1h[idx] = h;
        w1l[idx] = f2bf(w - bf2f(h));
    }
    // W2 frags: [64][16], same mu map, single M-tile
    for (int idx = tid; idx < 1024; idx += 256) {
        int j = idx & 7, lane = (idx >> 3) & 63, kt = idx >> 9;
        int mr = lane & 15, g = lane >> 4;
        int mu = 16 * (2 * kt + (j >> 2)) + 4 * g + (j & 3);
        float w = W2[mu * 16 + mr];
        unsigned short h = f2bf(w);
        w2h[idx] = h;
        w2l[idx] = f2bf(w - bf2f(h));
    }
    // bias frags: lane holds units 16*t + 4*g + r  (t=0..3, r=0..3)
    for (int idx = tid; idx < 1024; idx += 256) {
        int lane = idx >> 4, tr = idx & 15;
        int g = lane >> 4, t = tr >> 2, r = tr & 3;
        b0f[idx] = b0[16 * t + 4 * g + r];
        b1f[idx] = b1[16 * t + 4 * g + r];
    }
    for (int idx = tid; idx < 256; idx += 256) {
        int lane = idx >> 2, r = idx & 3, g = lane >> 4;
        b2f[idx] = b2[4 * g + r];
    }
}

// ---------------- main kernel: one wave computes 16 edges per iteration ----------------
__global__ __launch_bounds__(256, 2) void edge_mlp_kernel(
    const float* __restrict__ edges, const float* __restrict__ nodes,
    const float* __restrict__ globals_, const int* __restrict__ senders,
    const int* __restrict__ receivers, const int* __restrict__ gids,
    const void* __restrict__ ws, float* __restrict__ out, int n_tiles) {

    const unsigned short* w0h = (const unsigned short*)ws;
    const unsigned short* w0l = w0h + 4096;
    const unsigned short* w1h = w0h + 8192;
    const unsigned short* w1l = w0h + 12288;
    const unsigned short* w2h = w0h + 16384;
    const unsigned short* w2l = w0h + 17408;
    const float* b0f = (const float*)(w0h + 18432);
    const float* b1f = b0f + 1024;
    const float* b2f = b0f + 2048;

    const int lane = threadIdx.x & 63;
    const int wv = threadIdx.x >> 6;
    const int mr = lane & 15;
    const int g = lane >> 4;

    // ---- load weight fragments (L2-hot, once per block) ----
    short8 W0H[4][2], W0L[4][2], W1H[4][2], W1L[4][2], W2H[2], W2L[2];
#pragma unroll
    for (int t = 0; t < 4; ++t)
#pragma unroll
        for (int kt = 0; kt < 2; ++kt) {
            int o = ((t * 2 + kt) * 64 + lane) * 8;
            W0H[t][kt] = *(const short8*)(w0h + o);
            W0L[t][kt] = *(const short8*)(w0l + o);
            W1H[t][kt] = *(const short8*)(w1h + o);
            W1L[t][kt] = *(const short8*)(w1l + o);
        }
#pragma unroll
    for (int kt = 0; kt < 2; ++kt) {
        int o = (kt * 64 + lane) * 8;
        W2H[kt] = *(const short8*)(w2h + o);
        W2L[kt] = *(const short8*)(w2l + o);
    }
    float B0[16], B1[16], B2[4];
#pragma unroll
    for (int i = 0; i < 16; ++i) { B0[i] = b0f[lane * 16 + i]; B1[i] = b1f[lane * 16 + i]; }
#pragma unroll
    for (int i = 0; i < 4; ++i) B2[i] = b2f[lane * 4 + i];

    const int stride = gridDim.x * 4;
    for (int tile = blockIdx.x * 4 + wv; tile < n_tiles; tile += stride) {
        const int e = tile * 16 + mr;   // this lane's edge (column of B fragment)
        const int ri = receivers[e];
        const int si = senders[e];
        const int gi = gids[e];

        // gather 8 floats per k-tile per lane (k-slot map mu0 = 32*kt + 8*g + j)
        const float* p0 = (g < 2) ? (edges + (size_t)e * 16 + 8 * g)
                                  : (nodes + (size_t)ri * 16 + 8 * (g - 2));
        const float* p1 = (g < 2) ? (nodes + (size_t)si * 16 + 8 * g)
                                  : (globals_ + (size_t)gi * 16 + 8 * (g - 2));
        f32x4 x0 = *(const f32x4*)p0;
        f32x4 x1 = *(const f32x4*)(p0 + 4);
        f32x4 x2 = *(const f32x4*)p1;
        f32x4 x3 = *(const f32x4*)(p1 + 4);

        float xs[16];
#pragma unroll
        for (int i = 0; i < 4; ++i) { xs[i] = x0[i]; xs[4 + i] = x1[i]; xs[8 + i] = x2[i]; xs[12 + i] = x3[i]; }
        short8 XH[2], XL[2];
#pragma unroll
        for (int kt = 0; kt < 2; ++kt)
#pragma unroll
            for (int j = 0; j < 8; ++j) {
                float v = xs[kt * 8 + j];
                unsigned short h = f2bf(v);
                XH[kt][j] = (short)h;
                XL[kt][j] = (short)f2bf(v - bf2f(h));
            }

        // ---- layer 0: D = W0^T @ x^T  (hi/lo split: Wl*Xh + Wh*Xl + Wh*Xh) ----
        f32x4 acc0[4];
#pragma unroll
        for (int t = 0; t < 4; ++t) {
            f32x4 a = {0.f, 0.f, 0.f, 0.f};
            a = __builtin_amdgcn_mfma_f32_16x16x32_bf16(W0L[t][0], XH[0], a, 0, 0, 0);
            a = __builtin_amdgcn_mfma_f32_16x16x32_bf16(W0L[t][1], XH[1], a, 0, 0, 0);
            a = __builtin_amdgcn_mfma_f32_16x16x32_bf16(W0H[t][0], XL[0], a, 0, 0, 0);
            a = __builtin_amdgcn_mfma_f32_16x16x32_bf16(W0H[t][1], XL[1], a, 0, 0, 0);
            a = __builtin_amdgcn_mfma_f32_16x16x32_bf16(W0H[t][0], XH[0], a, 0, 0, 0);
            a = __builtin_amdgcn_mfma_f32_16x16x32_bf16(W0H[t][1], XH[1], a, 0, 0, 0);
            acc0[t] = a;
        }

        // bias + relu + repack (lane-local; j = 4*(t&1)+r, kt = t>>1)
        short8 HH[2], HL[2];
#pragma unroll
        for (int t = 0; t < 4; ++t)
#pragma unroll
            for (int r = 0; r < 4; ++r) {
                float v = acc0[t][r] + B0[t * 4 + r];
                v = fmaxf(v, 0.0f);
                int kt = t >> 1;
                int j = ((t & 1) << 2) | r;
                unsigned short h = f2bf(v);
                HH[kt][j] = (short)h;
                HL[kt][j] = (short)f2bf(v - bf2f(h));
            }

        // ---- layer 1 ----
        f32x4 acc1[4];
#pragma unroll
        for (int t = 0; t < 4; ++t) {
            f32x4 a = {0.f, 0.f, 0.f, 0.f};
            a = __builtin_amdgcn_mfma_f32_16x16x32_bf16(W1L[t][0], HH[0], a, 0, 0, 0);
            a = __builtin_amdgcn_mfma_f32_16x16x32_bf16(W1L[t][1], HH[1], a, 0, 0, 0);
            a = __builtin_amdgcn_mfma_f32_16x16x32_bf16(W1H[t][0], HL[0], a, 0, 0, 0);
            a = __builtin_amdgcn_mfma_f32_16x16x32_bf16(W1H[t][1], HL[1], a, 0, 0, 0);
            a = __builtin_amdgcn_mfma_f32_16x16x32_bf16(W1H[t][0], HH[0], a, 0, 0, 0);
            a = __builtin_amdgcn_mfma_f32_16x16x32_bf16(W1H[t][1], HH[1], a, 0, 0, 0);
            acc1[t] = a;
        }

        short8 GH[2], GL[2];
#pragma unroll
        for (int t = 0; t < 4; ++t)
#pragma unroll
            for (int r = 0; r < 4; ++r) {
                float v = acc1[t][r] + B1[t * 4 + r];
                v = fmaxf(v, 0.0f);
                int kt = t >> 1;
                int j = ((t & 1) << 2) | r;
                unsigned short h = f2bf(v);
                GH[kt][j] = (short)h;
                GL[kt][j] = (short)f2bf(v - bf2f(h));
            }

        // ---- layer 2 (single M-tile) ----
        f32x4 o = {0.f, 0.f, 0.f, 0.f};
        o = __builtin_amdgcn_mfma_f32_16x16x32_bf16(W2L[0], GH[0], o, 0, 0, 0);
        o = __builtin_amdgcn_mfma_f32_16x16x32_bf16(W2L[1], GH[1], o, 0, 0, 0);
        o = __builtin_amdgcn_mfma_f32_16x16x32_bf16(W2H[0], GL[0], o, 0, 0, 0);
        o = __builtin_amdgcn_mfma_f32_16x16x32_bf16(W2H[1], GL[1], o, 0, 0, 0);
        o = __builtin_amdgcn_mfma_f32_16x16x32_bf16(W2H[0], GH[0], o, 0, 0, 0);
        o = __builtin_amdgcn_mfma_f32_16x16x32_bf16(W2H[1], GH[1], o, 0, 0, 0);

        f32x4 res;
#pragma unroll
        for (int r = 0; r < 4; ++r) res[r] = o[r] + B2[r];
        *(f32x4*)(out + (size_t)e * 16 + 4 * g) = res;  // row e, cols 4g..4g+3
    }
}

extern "C" void kernel_launch(void* const* d_in, const int* in_sizes, int n_in,
                              void* d_out, int out_size, void* d_ws, size_t ws_size,
                              hipStream_t stream) {
    const float* edges    = (const float*)d_in[0];
    const float* nodes    = (const float*)d_in[1];
    const float* globals_ = (const float*)d_in[2];
    const float* W0 = (const float*)d_in[3];
    const float* b0 = (const float*)d_in[4];
    const float* W1 = (const float*)d_in[5];
    const float* b1 = (const float*)d_in[6];
    const float* W2 = (const float*)d_in[7];
    const float* b2 = (const float*)d_in[8];
    const int* senders   = (const int*)d_in[9];
    const int* receivers = (const int*)d_in[10];
    const int* gids      = (const int*)d_in[11];
    float* out = (float*)d_out;

    const int n_edges = in_sizes[9];          // 1,600,000
    const int n_tiles = E_DIV16(n_edges);     // 16-edge wave tiles

    prep_kernel<<<1, 256, 0, stream>>>(W0, b0, W1, b1, W2, b2, d_ws);

    int grid = (n_tiles + 3) / 4;
    if (grid > 2048) grid = 2048;
    edge_mlp_kernel<<<grid, 256, 0, stream>>>(edges, nodes, globals_, senders, receivers,
                                              gids, d_ws, out, n_tiles);
}

// Round 2
// 282.244 us; speedup vs baseline: 1.1547x; 1.1547x over previous
//
#include <hip/hip_runtime.h>
#include <hip/hip_bf16.h>

// EdgeBlock: out[e] = (relu(relu(x@W0+b0)@W1+b1))@W2+b2, x = [edge|recv|send|glob] (64)
// bf16 hi/lo split MFMA (fp32-equivalent accuracy), transposed products so inter-layer
// data stays lane-local. R2: parallel prep, depth-2 software pipeline, cast-based
// bf16 split (cvt_pk), bias folded into MFMA C-init, nontemporal output stores.

typedef float f32x4 __attribute__((ext_vector_type(4)));
typedef short short8 __attribute__((ext_vector_type(8)));

__device__ __forceinline__ unsigned short f2bf(float f) {
    union { float f; unsigned int u; } v; v.f = f;
    unsigned int u = v.u;
    u += 0x7FFFu + ((u >> 16) & 1u);   // RNE
    return (unsigned short)(u >> 16);
}
__device__ __forceinline__ float bf2f(unsigned short b) {
    union { unsigned int u; float f; } v; v.u = ((unsigned int)b) << 16;
    return v.f;
}
// fast split: hi = RNE bf16 of v (via hw cvt), lo = RNE bf16 of residual
__device__ __forceinline__ void bfsplit(float v, unsigned short& h, unsigned short& l) {
    union { __hip_bfloat16 b; unsigned short u; } ch, cl;
    ch.b = __float2bfloat16(v);
    float r = v - __bfloat162float(ch.b);
    cl.b = __float2bfloat16(r);
    h = ch.u; l = cl.u;
}

// ---------------- prep: pack weights/biases into MFMA fragment layout in ws -------------
// ws layout (ushort units):
//   w0h[4096] w0l[4096] w1h[4096] w1l[4096] w2h[1024] w2l[1024]   (frags: [f][lane][j])
// then (float units): b0f[64][16] b1f[64][16] b2f[64][4]
__global__ void prep_kernel(const float* __restrict__ W0, const float* __restrict__ b0,
                            const float* __restrict__ W1, const float* __restrict__ b1,
                            const float* __restrict__ W2, const float* __restrict__ b2,
                            void* __restrict__ ws) {
    unsigned short* w0h = (unsigned short*)ws;
    unsigned short* w0l = w0h + 4096;
    unsigned short* w1h = w0h + 8192;
    unsigned short* w1l = w0h + 12288;
    unsigned short* w2h = w0h + 16384;
    unsigned short* w2l = w0h + 17408;
    float* b0f = (float*)(w0h + 18432);
    float* b1f = b0f + 1024;
    float* b2f = b0f + 2048;
    const int tid = blockIdx.x * blockDim.x + threadIdx.x;
    const int gstride = gridDim.x * blockDim.x;

    // W0 frags: A[m=hid][k=in] = W0[k][m]; k-slot map mu0 = 32*kt + 8*g + j
    for (int idx = tid; idx < 4096; idx += gstride) {
        int j = idx & 7, lane = (idx >> 3) & 63, f = idx >> 9;
        int t = f >> 1, kt = f & 1, mr = lane & 15, g = lane >> 4;
        float w = W0[(32 * kt + 8 * g + j) * 64 + (16 * t + mr)];
        unsigned short h = f2bf(w);
        w0h[idx] = h;
        w0l[idx] = f2bf(w - bf2f(h));
    }
    // W1 frags: k-slot map mu = 16*(2*kt + (j>>2)) + 4*g + (j&3)  (matches layer-0 output layout)
    for (int idx = tid; idx < 4096; idx += gstride) {
        int j = idx & 7, lane = (idx >> 3) & 63, f = idx >> 9;
        int t = f >> 1, kt = f & 1, mr = lane & 15, g = lane >> 4;
        int mu = 16 * (2 * kt + (j >> 2)) + 4 * g + (j & 3);
        float w = W1[mu * 64 + (16 * t + mr)];
        unsigned short h = f2bf(w);
        w1h[idx] = h;
        w1l[idx] = f2bf(w - bf2f(h));
    }
    // W2 frags: [64][16], same mu map, single M-tile
    for (int idx = tid; idx < 1024; idx += gstride) {
        int j = idx & 7, lane = (idx >> 3) & 63, kt = idx >> 9;
        int mr = lane & 15, g = lane >> 4;
        int mu = 16 * (2 * kt + (j >> 2)) + 4 * g + (j & 3);
        float w = W2[mu * 16 + mr];
        unsigned short h = f2bf(w);
        w2h[idx] = h;
        w2l[idx] = f2bf(w - bf2f(h));
    }
    // bias frags: lane holds units 16*t + 4*g + r  (t=0..3, r=0..3)
    for (int idx = tid; idx < 1024; idx += gstride) {
        int lane = idx >> 4, tr = idx & 15;
        int g = lane >> 4, t = tr >> 2, r = tr & 3;
        b0f[idx] = b0[16 * t + 4 * g + r];
        b1f[idx] = b1[16 * t + 4 * g + r];
    }
    for (int idx = tid; idx < 256; idx += gstride) {
        int lane = idx >> 2, r = idx & 3, g = lane >> 4;
        b2f[idx] = b2[4 * g + r];
    }
}

// ---------------- main kernel: one wave computes 16 edges per iteration ----------------
__global__ __launch_bounds__(256, 2) void edge_mlp_kernel(
    const float* __restrict__ edges, const float* __restrict__ nodes,
    const float* __restrict__ globals_, const int* __restrict__ senders,
    const int* __restrict__ receivers, const int* __restrict__ gids,
    const void* __restrict__ ws, float* __restrict__ out, int n_tiles, int iters) {

    const unsigned short* w0h = (const unsigned short*)ws;
    const unsigned short* w0l = w0h + 4096;
    const unsigned short* w1h = w0h + 8192;
    const unsigned short* w1l = w0h + 12288;
    const unsigned short* w2h = w0h + 16384;
    const unsigned short* w2l = w0h + 17408;
    const float* b0f = (const float*)(w0h + 18432);
    const float* b1f = b0f + 1024;
    const float* b2f = b0f + 2048;

    const int lane = threadIdx.x & 63;
    const int wv = threadIdx.x >> 6;
    const int mr = lane & 15;
    const int g = lane >> 4;

    // ---- load weight fragments (L2-hot, once per block) ----
    short8 W0H[4][2], W0L[4][2], W1H[4][2], W1L[4][2], W2H[2], W2L[2];
#pragma unroll
    for (int t = 0; t < 4; ++t)
#pragma unroll
        for (int kt = 0; kt < 2; ++kt) {
            int o = ((t * 2 + kt) * 64 + lane) * 8;
            W0H[t][kt] = *(const short8*)(w0h + o);
            W0L[t][kt] = *(const short8*)(w0l + o);
            W1H[t][kt] = *(const short8*)(w1h + o);
            W1L[t][kt] = *(const short8*)(w1l + o);
        }
#pragma unroll
    for (int kt = 0; kt < 2; ++kt) {
        int o = (kt * 64 + lane) * 8;
        W2H[kt] = *(const short8*)(w2h + o);
        W2L[kt] = *(const short8*)(w2l + o);
    }
    float B0[16], B1[16], B2[4];
#pragma unroll
    for (int i = 0; i < 16; ++i) { B0[i] = b0f[lane * 16 + i]; B1[i] = b1f[lane * 16 + i]; }
#pragma unroll
    for (int i = 0; i < 4; ++i) B2[i] = b2f[lane * 4 + i];

    const int W = gridDim.x << 2;                 // total waves
    const int wave_id = (blockIdx.x << 2) | wv;
    const int last = n_tiles - 1;

    // tile index for iteration i (clamped -> branchless, duplicate work is benign)
    #define TILE_OF(i) (((wave_id + (i) * W) < n_tiles) ? (wave_id + (i) * W) : last)

    // ---- pipeline prologue ----
    int e_cur = TILE_OF(0) * 16 + mr;
    {   // indices + gather for iteration 0
        int ri = receivers[e_cur], si = senders[e_cur], gi = gids[e_cur];
        (void)ri; (void)si; (void)gi;
    }
    int ri0 = receivers[e_cur], si0 = senders[e_cur], gi0 = gids[e_cur];
    const float* p0 = (g < 2) ? (edges + (size_t)e_cur * 16 + 8 * g)
                              : (nodes + (size_t)ri0 * 16 + 8 * (g - 2));
    const float* p1 = (g < 2) ? (nodes + (size_t)si0 * 16 + 8 * g)
                              : (globals_ + (size_t)gi0 * 16 + 8 * (g - 2));
    f32x4 x0 = *(const f32x4*)p0;
    f32x4 x1 = *(const f32x4*)(p0 + 4);
    f32x4 x2 = *(const f32x4*)p1;
    f32x4 x3 = *(const f32x4*)(p1 + 4);

    int e_nxt = TILE_OF(1) * 16 + mr;
    int ri_n = receivers[e_nxt], si_n = senders[e_nxt], gi_n = gids[e_nxt];

    for (int i = 0; i < iters; ++i) {
        // ---- prefetch data for iteration i+1 (indices already in regs) ----
        const float* q0 = (g < 2) ? (edges + (size_t)e_nxt * 16 + 8 * g)
                                  : (nodes + (size_t)ri_n * 16 + 8 * (g - 2));
        const float* q1 = (g < 2) ? (nodes + (size_t)si_n * 16 + 8 * g)
                                  : (globals_ + (size_t)gi_n * 16 + 8 * (g - 2));
        f32x4 n0 = *(const f32x4*)q0;
        f32x4 n1 = *(const f32x4*)(q0 + 4);
        f32x4 n2 = *(const f32x4*)q1;
        f32x4 n3 = *(const f32x4*)(q1 + 4);

        // ---- prefetch indices for iteration i+2 ----
        int e_nn = TILE_OF(i + 2) * 16 + mr;
        int ri_nn = receivers[e_nn], si_nn = senders[e_nn], gi_nn = gids[e_nn];

        // ---- compute current tile ----
        float xs[16];
#pragma unroll
        for (int k = 0; k < 4; ++k) { xs[k] = x0[k]; xs[4 + k] = x1[k]; xs[8 + k] = x2[k]; xs[12 + k] = x3[k]; }
        short8 XH[2], XL[2];
#pragma unroll
        for (int kt = 0; kt < 2; ++kt)
#pragma unroll
            for (int j = 0; j < 8; ++j) {
                unsigned short h, l;
                bfsplit(xs[kt * 8 + j], h, l);
                XH[kt][j] = (short)h;
                XL[kt][j] = (short)l;
            }

        // layer 0: D = W0^T @ x^T  (hi/lo: Wl*Xh + Wh*Xl + Wh*Xh), bias in C-init
        short8 HH[2], HL[2];
#pragma unroll
        for (int t = 0; t < 4; ++t) {
            f32x4 a = {B0[t * 4 + 0], B0[t * 4 + 1], B0[t * 4 + 2], B0[t * 4 + 3]};
            a = __builtin_amdgcn_mfma_f32_16x16x32_bf16(W0L[t][0], XH[0], a, 0, 0, 0);
            a = __builtin_amdgcn_mfma_f32_16x16x32_bf16(W0L[t][1], XH[1], a, 0, 0, 0);
            a = __builtin_amdgcn_mfma_f32_16x16x32_bf16(W0H[t][0], XL[0], a, 0, 0, 0);
            a = __builtin_amdgcn_mfma_f32_16x16x32_bf16(W0H[t][1], XL[1], a, 0, 0, 0);
            a = __builtin_amdgcn_mfma_f32_16x16x32_bf16(W0H[t][0], XH[0], a, 0, 0, 0);
            a = __builtin_amdgcn_mfma_f32_16x16x32_bf16(W0H[t][1], XH[1], a, 0, 0, 0);
#pragma unroll
            for (int r = 0; r < 4; ++r) {
                float v = fmaxf(a[r], 0.0f);
                int kt = t >> 1, j = ((t & 1) << 2) | r;
                unsigned short h, l;
                bfsplit(v, h, l);
                HH[kt][j] = (short)h;
                HL[kt][j] = (short)l;
            }
        }

        // layer 1
        short8 GH[2], GL[2];
#pragma unroll
        for (int t = 0; t < 4; ++t) {
            f32x4 a = {B1[t * 4 + 0], B1[t * 4 + 1], B1[t * 4 + 2], B1[t * 4 + 3]};
            a = __builtin_amdgcn_mfma_f32_16x16x32_bf16(W1L[t][0], HH[0], a, 0, 0, 0);
            a = __builtin_amdgcn_mfma_f32_16x16x32_bf16(W1L[t][1], HH[1], a, 0, 0, 0);
            a = __builtin_amdgcn_mfma_f32_16x16x32_bf16(W1H[t][0], HL[0], a, 0, 0, 0);
            a = __builtin_amdgcn_mfma_f32_16x16x32_bf16(W1H[t][1], HL[1], a, 0, 0, 0);
            a = __builtin_amdgcn_mfma_f32_16x16x32_bf16(W1H[t][0], HH[0], a, 0, 0, 0);
            a = __builtin_amdgcn_mfma_f32_16x16x32_bf16(W1H[t][1], HH[1], a, 0, 0, 0);
#pragma unroll
            for (int r = 0; r < 4; ++r) {
                float v = fmaxf(a[r], 0.0f);
                int kt = t >> 1, j = ((t & 1) << 2) | r;
                unsigned short h, l;
                bfsplit(v, h, l);
                GH[kt][j] = (short)h;
                GL[kt][j] = (short)l;
            }
        }

        // layer 2 (single M-tile), bias in C-init
        f32x4 o = {B2[0], B2[1], B2[2], B2[3]};
        o = __builtin_amdgcn_mfma_f32_16x16x32_bf16(W2L[0], GH[0], o, 0, 0, 0);
        o = __builtin_amdgcn_mfma_f32_16x16x32_bf16(W2L[1], GH[1], o, 0, 0, 0);
        o = __builtin_amdgcn_mfma_f32_16x16x32_bf16(W2H[0], GL[0], o, 0, 0, 0);
        o = __builtin_amdgcn_mfma_f32_16x16x32_bf16(W2H[1], GL[1], o, 0, 0, 0);
        o = __builtin_amdgcn_mfma_f32_16x16x32_bf16(W2H[0], GH[0], o, 0, 0, 0);
        o = __builtin_amdgcn_mfma_f32_16x16x32_bf16(W2H[1], GH[1], o, 0, 0, 0);

        __builtin_nontemporal_store(o, (f32x4*)(out + (size_t)e_cur * 16 + 4 * g));

        // ---- rotate pipeline state ----
        e_cur = e_nxt;
        x0 = n0; x1 = n1; x2 = n2; x3 = n3;
        e_nxt = e_nn; ri_n = ri_nn; si_n = si_nn; gi_n = gi_nn;
    }
    #undef TILE_OF
}

extern "C" void kernel_launch(void* const* d_in, const int* in_sizes, int n_in,
                              void* d_out, int out_size, void* d_ws, size_t ws_size,
                              hipStream_t stream) {
    const float* edges    = (const float*)d_in[0];
    const float* nodes    = (const float*)d_in[1];
    const float* globals_ = (const float*)d_in[2];
    const float* W0 = (const float*)d_in[3];
    const float* b0 = (const float*)d_in[4];
    const float* W1 = (const float*)d_in[5];
    const float* b1 = (const float*)d_in[6];
    const float* W2 = (const float*)d_in[7];
    const float* b2 = (const float*)d_in[8];
    const int* senders   = (const int*)d_in[9];
    const int* receivers = (const int*)d_in[10];
    const int* gids      = (const int*)d_in[11];
    float* out = (float*)d_out;

    const int n_edges = in_sizes[9];          // 1,600,000
    const int n_tiles = n_edges >> 4;         // 16-edge wave tiles

    prep_kernel<<<72, 256, 0, stream>>>(W0, b0, W1, b1, W2, b2, d_ws);

    int grid = 2500;                          // 10000 waves -> exactly 10 iters at E=1.6M
    if (grid > (n_tiles + 3) / 4) grid = (n_tiles + 3) / 4;
    const int waves = grid * 4;
    const int iters = (n_tiles + waves - 1) / waves;
    edge_mlp_kernel<<<grid, 256, 0, stream>>>(edges, nodes, globals_, senders, receivers,
                                              gids, d_ws, out, n_tiles, iters);
}